// Round 2
// baseline (35.907 us; speedup 1.0000x reference)
//
#include <hip/hip_runtime.h>
#include <math.h>

#define NCOLS 8
#define ENUM 12
#define EDIM 16
#define VPAD 20          // padded word stride per (col,vocab) row: 20v mod 32 has period 8 -> <=2-way bank conflict
#define NPAIR 28
#define TPB 256

// triu_indices(8, k=1) order
__device__ __constant__ const int kPI[NPAIR] = {0,0,0,0,0,0,0, 1,1,1,1,1,1, 2,2,2,2,2, 3,3,3,3, 4,4,4, 5,5, 6};
__device__ __constant__ const int kPJ[NPAIR] = {1,2,3,4,5,6,7, 2,3,4,5,6,7, 3,4,5,6,7, 4,5,6,7, 5,6,7, 6,7, 7};

__global__ void fm_zero_scalar(float* __restrict__ p) { *p = 0.0f; }

__global__ __launch_bounds__(TPB) void fm_main(
    const int*   __restrict__ idx,      // [8][B]
    const float* __restrict__ label,    // [B][2]
    const float* __restrict__ posw,     // [B][2]
    const float* __restrict__ noise,    // [B][16]
    const float* __restrict__ emb_mean, // [8][12][16]
    const float* __restrict__ emb_std,  // [8][12][16]
    const float* __restrict__ fc_w,     // [28][16]  (read via uniform scalar loads)
    const float* __restrict__ emb_act,  // [2][16]   (read via uniform scalar loads)
    float*       __restrict__ out,      // [B][2]
    float*       __restrict__ scalar_out, // &out[2B], pre-zeroed by fm_zero_scalar
    float invB, int B)
{
    __shared__ __align__(16) float s_mean[NCOLS * ENUM * VPAD];
    __shared__ __align__(16) float s_sp  [NCOLS * ENUM * VPAD];
    __shared__ float s_red[TPB / 64];

    // ---- stage gather tables into LDS; softplus computed once per table entry ----
    for (int t = threadIdx.x; t < NCOLS * ENUM * EDIM; t += TPB) {
        int cv = t >> 4, d = t & 15;
        float m = emb_mean[t];
        float x = emb_std[t];
        // stable softplus: max(x,0) + log1p(exp(-|x|)); fold the 0.01 scale in
        float sp = fmaxf(x, 0.0f) + log1pf(expf(-fabsf(x)));
        s_mean[cv * VPAD + d] = m;
        s_sp  [cv * VPAD + d] = 0.01f * sp;
    }
    __syncthreads();

    const int b = blockIdx.x * TPB + threadIdx.x;
    float lossv = 0.0f;

    if (b < B) {
        // noise[b][0..15]
        float nz[EDIM];
        {
            const float4* np4 = reinterpret_cast<const float4*>(noise + (size_t)b * EDIM);
            float4 a0 = np4[0], a1 = np4[1], a2 = np4[2], a3 = np4[3];
            nz[0]=a0.x; nz[1]=a0.y; nz[2]=a0.z; nz[3]=a0.w;
            nz[4]=a1.x; nz[5]=a1.y; nz[6]=a1.z; nz[7]=a1.w;
            nz[8]=a2.x; nz[9]=a2.y; nz[10]=a2.z; nz[11]=a2.w;
            nz[12]=a3.x; nz[13]=a3.y; nz[14]=a3.z; nz[15]=a3.w;
        }

        int base[NCOLS];
        #pragma unroll
        for (int c = 0; c < NCOLS; ++c) {
            int v = idx[(size_t)c * B + b];
            base[c] = (c * ENUM + v) * VPAD;
        }

        float inf_s = 0.0f, a0 = 0.0f, a1 = 0.0f;

        // two halves of d to cap register pressure: e[8][8] per half
        #pragma unroll
        for (int dh = 0; dh < 2; ++dh) {
            float e[NCOLS][8];
            float cs[8];
            #pragma unroll
            for (int k = 0; k < 8; ++k) cs[k] = 0.0f;

            #pragma unroll
            for (int c = 0; c < NCOLS; ++c) {
                float m[8], sv[8];
                const float* mp = &s_mean[base[c] + dh * 8];
                const float* pp = &s_sp  [base[c] + dh * 8];
                *reinterpret_cast<float4*>(&m[0])  = *reinterpret_cast<const float4*>(mp);
                *reinterpret_cast<float4*>(&m[4])  = *reinterpret_cast<const float4*>(mp + 4);
                *reinterpret_cast<float4*>(&sv[0]) = *reinterpret_cast<const float4*>(pp);
                *reinterpret_cast<float4*>(&sv[4]) = *reinterpret_cast<const float4*>(pp + 4);
                #pragma unroll
                for (int k = 0; k < 8; ++k) {
                    float ev = fmaf(sv[k], nz[dh * 8 + k], m[k]);
                    e[c][k] = ev;
                    cs[k] += ev;
                }
            }

            // pairwise products dotted with fc_w; fc_w indexed with compile-time
            // constants from a uniform kernel arg -> scalar (s_load) path, no LDS
            #pragma unroll
            for (int p = 0; p < NPAIR; ++p) {
                const int i = kPI[p], j = kPJ[p];
                #pragma unroll
                for (int k = 0; k < 8; ++k) {
                    inf_s = fmaf(e[i][k] * e[j][k], fc_w[p * EDIM + dh * 8 + k], inf_s);
                }
            }

            // action-embedding dots for this half (uniform scalar loads)
            #pragma unroll
            for (int k = 0; k < 8; ++k) {
                a0 = fmaf(cs[k], emb_act[dh * 8 + k], a0);
                a1 = fmaf(cs[k], emb_act[EDIM + dh * 8 + k], a1);
            }
        }

        float i0 = inf_s + a0;
        float i1 = inf_s + a1;

        float2 lb = reinterpret_cast<const float2*>(label)[b];
        float2 pw = reinterpret_cast<const float2*>(posw)[b];
        float d0 = i0 - lb.x;
        float d1 = i1 - lb.y;
        lossv = pw.x * d0 * d0 + pw.y * d1 * d1;

        reinterpret_cast<float2*>(out)[b] = make_float2(i0, i1);
    }

    // ---- block reduction of lossv, then one atomicAdd per block ----
    #pragma unroll
    for (int m = 32; m > 0; m >>= 1) lossv += __shfl_xor(lossv, m);
    const int wid = threadIdx.x >> 6;
    if ((threadIdx.x & 63) == 0) s_red[wid] = lossv;
    __syncthreads();
    if (threadIdx.x == 0) {
        float s = 0.0f;
        #pragma unroll
        for (int w = 0; w < TPB / 64; ++w) s += s_red[w];
        atomicAdd(scalar_out, s * invB);
    }
}

extern "C" void kernel_launch(void* const* d_in, const int* in_sizes, int n_in,
                              void* d_out, int out_size, void* d_ws, size_t ws_size,
                              hipStream_t stream) {
    const int*   idx      = (const int*)d_in[0];
    const float* label    = (const float*)d_in[1];
    const float* posw     = (const float*)d_in[2];
    const float* noise    = (const float*)d_in[3];
    const float* emb_mean = (const float*)d_in[4];
    const float* emb_std  = (const float*)d_in[5];
    const float* fc_w     = (const float*)d_in[6];
    const float* emb_act  = (const float*)d_in[7];
    float* out = (float*)d_out;

    const int B = in_sizes[0] / NCOLS;
    const int blocks = (B + TPB - 1) / TPB;
    float* scalar_out = out + (size_t)2 * B;

    // no d_ws usage anywhere: scalar loss accumulated via device atomics into
    // the pre-zeroed output slot (stream-ordered: zero -> main)
    fm_zero_scalar<<<1, 1, 0, stream>>>(scalar_out);
    fm_main<<<blocks, TPB, 0, stream>>>(idx, label, posw, noise, emb_mean, emb_std,
                                        fc_w, emb_act, out, scalar_out,
                                        1.0f / (float)B, B);
}

// Round 3
// 27.698 us; speedup vs baseline: 1.2964x; 1.2964x over previous
//
#include <hip/hip_runtime.h>
#include <math.h>

#define NCOLS 8
#define ENUM 12
#define EDIM 16
#define VPAD 20          // padded word stride: banks (20v+d)%32 spread, <=2-way conflict (free)
#define NPAIR 28
#define TPB 256
#define G 2              // elements per thread: amortizes fc_w/emb_act LDS broadcasts

// triu_indices(8, k=1) order
__device__ __constant__ const int kPI[NPAIR] = {0,0,0,0,0,0,0, 1,1,1,1,1,1, 2,2,2,2,2, 3,3,3,3, 4,4,4, 5,5, 6};
__device__ __constant__ const int kPJ[NPAIR] = {1,2,3,4,5,6,7, 2,3,4,5,6,7, 3,4,5,6,7, 4,5,6,7, 5,6,7, 6,7, 7};

__global__ void fm_zero_scalar(float* __restrict__ p) { *p = 0.0f; }

__global__ __launch_bounds__(TPB) void fm_main(
    const int*   __restrict__ idx,      // [8][B]
    const float* __restrict__ label,    // [B][2]
    const float* __restrict__ posw,     // [B][2]
    const float* __restrict__ noise,    // [B][16]
    const float* __restrict__ emb_mean, // [8][12][16]
    const float* __restrict__ emb_std,  // [8][12][16]
    const float* __restrict__ fc_w,     // [28][16]
    const float* __restrict__ emb_act,  // [2][16]
    float*       __restrict__ out,      // [B][2]
    float*       __restrict__ scalar_out,
    float invB, int B)
{
    __shared__ __align__(16) float s_mean[NCOLS * ENUM * VPAD];
    __shared__ __align__(16) float s_sp  [NCOLS * ENUM * VPAD];
    __shared__ __align__(16) float s_fcw [NPAIR * EDIM];
    __shared__ __align__(16) float s_ea  [2 * EDIM];
    __shared__ float s_red[TPB / 64];

    // ---- stage tables into LDS; softplus folded in once per table entry ----
    for (int t = threadIdx.x; t < NCOLS * ENUM * EDIM; t += TPB) {
        int cv = t >> 4, d = t & 15;
        float m = emb_mean[t];
        float x = emb_std[t];
        float sp = fmaxf(x, 0.0f) + log1pf(expf(-fabsf(x)));   // stable softplus
        s_mean[cv * VPAD + d] = m;
        s_sp  [cv * VPAD + d] = 0.01f * sp;
    }
    for (int t = threadIdx.x; t < NPAIR * EDIM; t += TPB) s_fcw[t] = fc_w[t];
    if (threadIdx.x < 2 * EDIM) s_ea[threadIdx.x] = emb_act[threadIdx.x];
    __syncthreads();

    // exact cover: B = gridDim.x * TPB * G, no tail branch -> uniform control flow
    const int b0 = blockIdx.x * (TPB * G) + threadIdx.x;   // element 0
    // element g is b0 + g*TPB

    // noise for both elements
    float nz[G][EDIM];
    #pragma unroll
    for (int g = 0; g < G; ++g) {
        const float4* np4 = reinterpret_cast<const float4*>(noise + (size_t)(b0 + g * TPB) * EDIM);
        float4 a0 = np4[0], a1 = np4[1], a2 = np4[2], a3 = np4[3];
        nz[g][0]=a0.x; nz[g][1]=a0.y; nz[g][2]=a0.z; nz[g][3]=a0.w;
        nz[g][4]=a1.x; nz[g][5]=a1.y; nz[g][6]=a1.z; nz[g][7]=a1.w;
        nz[g][8]=a2.x; nz[g][9]=a2.y; nz[g][10]=a2.z; nz[g][11]=a2.w;
        nz[g][12]=a3.x; nz[g][13]=a3.y; nz[g][14]=a3.z; nz[g][15]=a3.w;
    }

    int base[G][NCOLS];
    #pragma unroll
    for (int c = 0; c < NCOLS; ++c) {
        #pragma unroll
        for (int g = 0; g < G; ++g) {
            int v = idx[(size_t)c * B + b0 + g * TPB];
            base[g][c] = (c * ENUM + v) * VPAD;
        }
    }

    float inf_s[G] = {0.0f, 0.0f};
    float ad0[G]   = {0.0f, 0.0f};
    float ad1[G]   = {0.0f, 0.0f};

    // 4 quarters of d (4 dims each) to cap register pressure: e[G][8][4]
    #pragma unroll
    for (int q = 0; q < 4; ++q) {
        float e[G][NCOLS][4];
        float cs[G][4];
        #pragma unroll
        for (int g = 0; g < G; ++g)
            #pragma unroll
            for (int k = 0; k < 4; ++k) cs[g][k] = 0.0f;

        #pragma unroll
        for (int c = 0; c < NCOLS; ++c) {
            #pragma unroll
            for (int g = 0; g < G; ++g) {
                float m[4], sv[4];
                *reinterpret_cast<float4*>(m)  = *reinterpret_cast<const float4*>(&s_mean[base[g][c] + q * 4]);
                *reinterpret_cast<float4*>(sv) = *reinterpret_cast<const float4*>(&s_sp  [base[g][c] + q * 4]);
                #pragma unroll
                for (int k = 0; k < 4; ++k) {
                    float ev = fmaf(sv[k], nz[g][q * 4 + k], m[k]);
                    e[g][c][k] = ev;
                    cs[g][k] += ev;
                }
            }
        }

        // pair products: w read ONCE per pair per quarter, applied to both elements
        #pragma unroll
        for (int p = 0; p < NPAIR; ++p) {
            const int i = kPI[p], j = kPJ[p];
            float w[4];
            *reinterpret_cast<float4*>(w) = *reinterpret_cast<const float4*>(&s_fcw[p * EDIM + q * 4]);
            #pragma unroll
            for (int g = 0; g < G; ++g) {
                #pragma unroll
                for (int k = 0; k < 4; ++k)
                    inf_s[g] = fmaf(e[g][i][k] * e[g][j][k], w[k], inf_s[g]);
            }
        }

        // action-embedding dots for this quarter
        float ea0[4], ea1[4];
        *reinterpret_cast<float4*>(ea0) = *reinterpret_cast<const float4*>(&s_ea[q * 4]);
        *reinterpret_cast<float4*>(ea1) = *reinterpret_cast<const float4*>(&s_ea[EDIM + q * 4]);
        #pragma unroll
        for (int g = 0; g < G; ++g) {
            #pragma unroll
            for (int k = 0; k < 4; ++k) {
                ad0[g] = fmaf(cs[g][k], ea0[k], ad0[g]);
                ad1[g] = fmaf(cs[g][k], ea1[k], ad1[g]);
            }
        }
    }

    float lossv = 0.0f;
    #pragma unroll
    for (int g = 0; g < G; ++g) {
        const int b = b0 + g * TPB;
        float i0 = inf_s[g] + ad0[g];
        float i1 = inf_s[g] + ad1[g];
        float2 lb = reinterpret_cast<const float2*>(label)[b];
        float2 pw = reinterpret_cast<const float2*>(posw)[b];
        float d0 = i0 - lb.x;
        float d1 = i1 - lb.y;
        lossv += pw.x * d0 * d0 + pw.y * d1 * d1;
        reinterpret_cast<float2*>(out)[b] = make_float2(i0, i1);
    }

    // ---- block reduction, one atomicAdd per block into pre-zeroed slot ----
    #pragma unroll
    for (int m = 32; m > 0; m >>= 1) lossv += __shfl_xor(lossv, m);
    const int wid = threadIdx.x >> 6;
    if ((threadIdx.x & 63) == 0) s_red[wid] = lossv;
    __syncthreads();
    if (threadIdx.x == 0) {
        float s = 0.0f;
        #pragma unroll
        for (int w = 0; w < TPB / 64; ++w) s += s_red[w];
        atomicAdd(scalar_out, s * invB);
    }
}

extern "C" void kernel_launch(void* const* d_in, const int* in_sizes, int n_in,
                              void* d_out, int out_size, void* d_ws, size_t ws_size,
                              hipStream_t stream) {
    const int*   idx      = (const int*)d_in[0];
    const float* label    = (const float*)d_in[1];
    const float* posw     = (const float*)d_in[2];
    const float* noise    = (const float*)d_in[3];
    const float* emb_mean = (const float*)d_in[4];
    const float* emb_std  = (const float*)d_in[5];
    const float* fc_w     = (const float*)d_in[6];
    const float* emb_act  = (const float*)d_in[7];
    float* out = (float*)d_out;

    const int B = in_sizes[0] / NCOLS;
    const int blocks = B / (TPB * G);          // 262144/512 = 512, exact
    float* scalar_out = out + (size_t)2 * B;

    fm_zero_scalar<<<1, 1, 0, stream>>>(scalar_out);
    fm_main<<<blocks, TPB, 0, stream>>>(idx, label, posw, noise, emb_mean, emb_std,
                                        fc_w, emb_act, out, scalar_out,
                                        1.0f / (float)B, B);
}